// Round 3
// baseline (1120.245 us; speedup 1.0000x reference)
//
#include <hip/hip_runtime.h>

// GMMNet: B=4,S=8,C=3,H=W=384,K=5. Pointwise per pixel; scan over S carries
// per-pixel state (pi[5], mu[15], rinv[5]=1/sigma) in registers.
// Round 3 change: __launch_bounds__(256,4) caps VGPRs at 128 so 4 waves/SIMD
// are resident (round 2: 188 VGPR -> 2 waves/SIMD, latency-bound at
// VALUBusy=33%). Weights stay in LDS (broadcast reads, pipelined); next
// frame's pixels prefetched at top of each s-iteration.

namespace {

constexpr int Kk = 5;
constexpr int Cc = 3;
constexpr int CKc = 15;   // C*K
constexpr int Bb = 4;
constexpr int Ss = 8;
constexpr int HWc = 384 * 384;

// LDS layout (float offsets); bases/pitches %4==0 -> ds_read_b128-mergeable.
constexpr int PW1 = 0,   PP1 = 12;  // pi_w1  5x10
constexpr int PB1 = 60;             // pi_b1  5 (pad 8)
constexpr int PW2 = 68,  PP2 = 8;   // pi_w2  5x5
constexpr int PB2 = 108;            // pi_b2  5 (pad 8)
constexpr int MW1 = 116, MP1 = 24;  // mu_w1  15x23
constexpr int MB1 = 476;            // mu_b1  15 (pad 16)
constexpr int MW2 = 492, MP2 = 16;  // mu_w2  15x15
constexpr int MB2 = 732;            // mu_b2  15 (pad 16)
constexpr int SW1 = 748, SP1 = 24;  // sg_w1  5x23
constexpr int SB1 = 868;            // sg_b1  5 (pad 8)
constexpr int SW2 = 876, SP2 = 8;   // sg_w2  5x5
constexpr int SB2 = 916;            // sg_b2  5 (pad 8)
constexpr int GW1 = 924, GP1 = 8;   // ga_w1  5x5
constexpr int GB1 = 964;            // ga_b1  5 (pad 8)
constexpr int GW2 = 972;            // ga_w2  5 (pad 8)
constexpr int GB2 = 980;            // ga_b2  1 (pad 4)
constexpr int WTOT = 984;           // 3936 B

__device__ __forceinline__ float rcpf(float x) { return __builtin_amdgcn_rcpf(x); }
__device__ __forceinline__ float sigm(float x) { return rcpf(1.0f + __expf(-x)); }
__device__ __forceinline__ float relu(float x) { return fmaxf(x, 0.0f); }

__device__ __forceinline__ void stage(float* W, int dst, const float* __restrict__ src,
                                      int rows, int cols, int pitch, int tid) {
    for (int t = tid; t < rows * pitch; t += 256) {
        int r = t / pitch, c = t - r * pitch;
        W[dst + t] = (c < cols) ? src[r * cols + c] : 0.0f;
    }
}

__global__ __launch_bounds__(256, 4) void gmm_seq_kernel(
    const float* __restrict__ frames,
    const float* __restrict__ mu0,
    const float* __restrict__ pw1, const float* __restrict__ pb1,
    const float* __restrict__ pw2, const float* __restrict__ pb2,
    const float* __restrict__ mw1, const float* __restrict__ mb1,
    const float* __restrict__ mw2, const float* __restrict__ mb2,
    const float* __restrict__ sw1, const float* __restrict__ sb1,
    const float* __restrict__ sw2, const float* __restrict__ sb2,
    const float* __restrict__ gw1, const float* __restrict__ gb1,
    const float* __restrict__ gw2, const float* __restrict__ gb2,
    float* __restrict__ out)
{
    __shared__ float sW[WTOT];
    {
        const int t = threadIdx.x;
        stage(sW, PW1, pw1, Kk, 2 * Kk, PP1, t);
        stage(sW, PB1, pb1, 1, Kk, 8, t);
        stage(sW, PW2, pw2, Kk, Kk, PP2, t);
        stage(sW, PB2, pb2, 1, Kk, 8, t);
        stage(sW, MW1, mw1, CKc, 23, MP1, t);
        stage(sW, MB1, mb1, 1, CKc, 16, t);
        stage(sW, MW2, mw2, CKc, CKc, MP2, t);
        stage(sW, MB2, mb2, 1, CKc, 16, t);
        stage(sW, SW1, sw1, Kk, 23, SP1, t);
        stage(sW, SB1, sb1, 1, Kk, 8, t);
        stage(sW, SW2, sw2, Kk, Kk, SP2, t);
        stage(sW, SB2, sb2, 1, Kk, 8, t);
        stage(sW, GW1, gw1, Kk, Kk, GP1, t);
        stage(sW, GB1, gb1, 1, Kk, 8, t);
        stage(sW, GW2, gw2, 1, Kk, 8, t);
        stage(sW, GB2, gb2, 1, 1, 4, t);
    }
    __syncthreads();

    const int tid = blockIdx.x * blockDim.x + threadIdx.x;
    const int b  = tid / HWc;
    const int hw = tid - b * HWc;

    const float C0 = 0.06349363593424097f;   // (2*pi)^{-3/2}

    // Per-pixel carried state.
    float pi[Kk], mu[CKc], rinv[Kk];         // rinv = 1/sigma
#pragma unroll
    for (int k = 0; k < Kk; k++) { pi[k] = 0.2f; rinv[k] = 1.0f; }
    {
        const float* mp = mu0 + (size_t)b * CKc * HWc + hw;
#pragma unroll
        for (int j = 0; j < CKc; j++) mu[j] = mp[(size_t)j * HWc];
    }

    const float* fbase = frames + ((size_t)b * Ss * Cc) * HWc + hw;
    float x[Cc];
#pragma unroll
    for (int c = 0; c < Cc; c++) x[c] = fbase[(size_t)c * HWc];

#pragma unroll 1
    for (int s = 0; s < Ss; s++) {
        // Prefetch next frame's pixel (hides global latency behind this step).
        float xn[Cc];
        if (s + 1 < Ss) {
            const float* fp = fbase + ((size_t)(s + 1) * Cc) * HWc;
#pragma unroll
            for (int c = 0; c < Cc; c++) xn[c] = fp[(size_t)c * HWc];
        }

        // ---- density(x; mu, 1/rinv) ----
        float dens[Kk];
#pragma unroll
        for (int k = 0; k < Kk; k++) {
            float inv_s2 = rinv[k] * rinv[k];
            float d0 = x[0] - mu[k * Cc + 0];
            float d1 = x[1] - mu[k * Cc + 1];
            float d2 = x[2] - mu[k * Cc + 2];
            float dist = d0 * d0 + d1 * d1 + d2 * d2;
            float coef = C0 * inv_s2 * rinv[k];            // C0 * rinv^3
            dens[k] = coef * __expf(-0.5f * dist * inv_s2);
        }

        float alpha[Kk], rho[Kk];
#pragma unroll
        for (int k = 0; k < Kk; k++) { alpha[k] = pi[k] * dens[k]; rho[k] = alpha[k] * dens[k]; }

        // ---- pi MLP (10 -> 5 -> 5) + softmax over K ----
        float piN[Kk];
        {
            float in[2 * Kk];
#pragma unroll
            for (int k = 0; k < Kk; k++) { in[k] = pi[k]; in[Kk + k] = alpha[k]; }
            float h[Kk];
#pragma unroll
            for (int j = 0; j < Kk; j++) {
                float a = sW[PB1 + j];
#pragma unroll
                for (int i = 0; i < 2 * Kk; i++) a = fmaf(sW[PW1 + j * PP1 + i], in[i], a);
                h[j] = relu(a);
            }
            float o[Kk];
            float m = -1e30f;
#pragma unroll
            for (int j = 0; j < Kk; j++) {
                float a = sW[PB2 + j];
#pragma unroll
                for (int i = 0; i < Kk; i++) a = fmaf(sW[PW2 + j * PP2 + i], h[i], a);
                o[j] = a; m = fmaxf(m, a);
            }
            float sum = 0.0f;
#pragma unroll
            for (int j = 0; j < Kk; j++) { o[j] = __expf(o[j] - m); sum += o[j]; }
            float r = rcpf(sum);
#pragma unroll
            for (int j = 0; j < Kk; j++) piN[j] = o[j] * r;
        }

        // ---- shared input vector for mu/sigma MLPs ----
        float in23[23];
        in23[0] = x[0]; in23[1] = x[1]; in23[2] = x[2];
#pragma unroll
        for (int j = 0; j < CKc; j++) in23[3 + j] = mu[j];
#pragma unroll
        for (int k = 0; k < Kk; k++) in23[18 + k] = rho[k];

        // ---- mu MLP (23 -> 15 -> 15), sigmoid ----
        float muN[CKc];
        {
            float h[CKc];
#pragma unroll
            for (int j = 0; j < CKc; j++) {
                float a = sW[MB1 + j];
#pragma unroll
                for (int i = 0; i < 23; i++) a = fmaf(sW[MW1 + j * MP1 + i], in23[i], a);
                h[j] = relu(a);
            }
#pragma unroll
            for (int j = 0; j < CKc; j++) {
                float a = sW[MB2 + j];
#pragma unroll
                for (int i = 0; i < CKc; i++) a = fmaf(sW[MW2 + j * MP2 + i], h[i], a);
                muN[j] = sigm(a);
            }
        }

        // ---- sigma MLP (23 -> 5 -> 5): rinvN = exp(-relu(a)) ----
#pragma unroll
        for (int j = 0; j < CKc; j++) in23[3 + j] = muN[j];   // reuse x, rho slots
        float rinvN[Kk];
        {
            float h[Kk];
#pragma unroll
            for (int j = 0; j < Kk; j++) {
                float a = sW[SB1 + j];
#pragma unroll
                for (int i = 0; i < 23; i++) a = fmaf(sW[SW1 + j * SP1 + i], in23[i], a);
                h[j] = relu(a);
            }
#pragma unroll
            for (int j = 0; j < Kk; j++) {
                float a = sW[SB2 + j];
#pragma unroll
                for (int i = 0; i < Kk; i++) a = fmaf(sW[SW2 + j * SP2 + i], h[i], a);
                rinvN[j] = __expf(-relu(a));
            }
        }

        // ---- dens2(x; muN, 1/rinvN), gamma MLP (5 -> 5 -> 1), sigmoid ----
        float gin[Kk];
#pragma unroll
        for (int k = 0; k < Kk; k++) {
            float inv_s2 = rinvN[k] * rinvN[k];
            float d0 = x[0] - muN[k * Cc + 0];
            float d1 = x[1] - muN[k * Cc + 1];
            float d2 = x[2] - muN[k * Cc + 2];
            float dist = d0 * d0 + d1 * d1 + d2 * d2;
            float coef = C0 * inv_s2 * rinvN[k];
            gin[k] = piN[k] * (coef * __expf(-0.5f * dist * inv_s2));
        }
        {
            float h[Kk];
#pragma unroll
            for (int j = 0; j < Kk; j++) {
                float a = sW[GB1 + j];
#pragma unroll
                for (int i = 0; i < Kk; i++) a = fmaf(sW[GW1 + j * GP1 + i], gin[i], a);
                h[j] = relu(a);
            }
            float go = sW[GB2];
#pragma unroll
            for (int i = 0; i < Kk; i++) go = fmaf(sW[GW2 + i], h[i], go);
            out[(size_t)(b * Ss + s) * HWc + hw] = sigm(go);
        }

        // ---- carry state ----
#pragma unroll
        for (int k = 0; k < Kk; k++) { pi[k] = piN[k]; rinv[k] = rinvN[k]; }
#pragma unroll
        for (int j = 0; j < CKc; j++) mu[j] = muN[j];
#pragma unroll
        for (int c = 0; c < Cc; c++) x[c] = xn[c];
    }
}

} // namespace

extern "C" void kernel_launch(void* const* d_in, const int* in_sizes, int n_in,
                              void* d_out, int out_size, void* d_ws, size_t ws_size,
                              hipStream_t stream) {
    const float* frames = (const float*)d_in[0];
    const float* mu0    = (const float*)d_in[2];
    const float* pw1 = (const float*)d_in[3];
    const float* pb1 = (const float*)d_in[4];
    const float* pw2 = (const float*)d_in[5];
    const float* pb2 = (const float*)d_in[6];
    const float* mw1 = (const float*)d_in[7];
    const float* mb1 = (const float*)d_in[8];
    const float* mw2 = (const float*)d_in[9];
    const float* mb2 = (const float*)d_in[10];
    const float* sw1 = (const float*)d_in[11];
    const float* sb1 = (const float*)d_in[12];
    const float* sw2 = (const float*)d_in[13];
    const float* sb2 = (const float*)d_in[14];
    const float* gw1 = (const float*)d_in[15];
    const float* gb1 = (const float*)d_in[16];
    const float* gw2 = (const float*)d_in[17];
    const float* gb2 = (const float*)d_in[18];
    float* out = (float*)d_out;

    const int total = Bb * HWc;          // 589,824 pixels
    const int block = 256;
    const int grid = (total + block - 1) / block;   // 2304 blocks

    gmm_seq_kernel<<<grid, block, 0, stream>>>(
        frames, mu0,
        pw1, pb1, pw2, pb2,
        mw1, mb1, mw2, mb2,
        sw1, sb1, sw2, sb2,
        gw1, gb1, gw2, gb2,
        out);
}

// Round 4
// 336.457 us; speedup vs baseline: 3.3295x; 3.3295x over previous
//
#include <hip/hip_runtime.h>

// GMMNet: B=4,S=8,C=3,H=W=384,K=5. Pointwise per pixel; scan over S carries
// per-pixel state (pi[5], mu[15], rinv[5]=1/sigma) in registers.
//
// Round 4: round-3's __launch_bounds__(256,4) caused catastrophic scratch
// spill (VGPR 64, FETCH 45MB->2.25GB). Root cause of round-2's 188 VGPR was
// machine-LICM hoisting ~100 loop-invariant LDS weight reads into registers.
// Fix: weight reads go through an asm-volatile-opaque LDS offset (woff) that
// changes "unpredictably" each s-iteration -> loads are loop-variant, cannot
// be hoisted, weights re-read from LDS each step (broadcast, cheap). True
// register demand (~90-110) then fits ~4 waves/SIMD with no cap and no spill.

namespace {

constexpr int Kk = 5;
constexpr int Cc = 3;
constexpr int CKc = 15;   // C*K
constexpr int Bb = 4;
constexpr int Ss = 8;
constexpr int HWc = 384 * 384;

// LDS layout (float offsets); bases/pitches %4==0 -> 16B-aligned rows,
// so constant-offset groups can merge into ds_read_b128 / ds_read2_b32.
constexpr int PW1 = 0,   PP1 = 12;  // pi_w1  5x10
constexpr int PB1 = 60;             // pi_b1  5 (pad 8)
constexpr int PW2 = 68,  PP2 = 8;   // pi_w2  5x5
constexpr int PB2 = 108;            // pi_b2  5 (pad 8)
constexpr int MW1 = 116, MP1 = 24;  // mu_w1  15x23
constexpr int MB1 = 476;            // mu_b1  15 (pad 16)
constexpr int MW2 = 492, MP2 = 16;  // mu_w2  15x15
constexpr int MB2 = 732;            // mu_b2  15 (pad 16)
constexpr int SW1 = 748, SP1 = 24;  // sg_w1  5x23
constexpr int SB1 = 868;            // sg_b1  5 (pad 8)
constexpr int SW2 = 876, SP2 = 8;   // sg_w2  5x5
constexpr int SB2 = 916;            // sg_b2  5 (pad 8)
constexpr int GW1 = 924, GP1 = 8;   // ga_w1  5x5
constexpr int GB1 = 964;            // ga_b1  5 (pad 8)
constexpr int GW2 = 972;            // ga_w2  5 (pad 8)
constexpr int GB2 = 980;            // ga_b2  1 (pad 4)
constexpr int WTOT = 984;           // 3936 B

__device__ __forceinline__ float rcpf(float x) { return __builtin_amdgcn_rcpf(x); }
__device__ __forceinline__ float sigm(float x) { return rcpf(1.0f + __expf(-x)); }
__device__ __forceinline__ float relu(float x) { return fmaxf(x, 0.0f); }

__device__ __forceinline__ void stage(float* W, int dst, const float* __restrict__ src,
                                      int rows, int cols, int pitch, int tid) {
    for (int t = tid; t < rows * pitch; t += 256) {
        int r = t / pitch, c = t - r * pitch;
        W[dst + t] = (c < cols) ? src[r * cols + c] : 0.0f;
    }
}

__global__ __launch_bounds__(256) void gmm_seq_kernel(
    const float* __restrict__ frames,
    const float* __restrict__ mu0,
    const float* __restrict__ pw1, const float* __restrict__ pb1,
    const float* __restrict__ pw2, const float* __restrict__ pb2,
    const float* __restrict__ mw1, const float* __restrict__ mb1,
    const float* __restrict__ mw2, const float* __restrict__ mb2,
    const float* __restrict__ sw1, const float* __restrict__ sb1,
    const float* __restrict__ sw2, const float* __restrict__ sb2,
    const float* __restrict__ gw1, const float* __restrict__ gb1,
    const float* __restrict__ gw2, const float* __restrict__ gb2,
    float* __restrict__ out)
{
    __shared__ float sW[WTOT];
    {
        const int t = threadIdx.x;
        stage(sW, PW1, pw1, Kk, 2 * Kk, PP1, t);
        stage(sW, PB1, pb1, 1, Kk, 8, t);
        stage(sW, PW2, pw2, Kk, Kk, PP2, t);
        stage(sW, PB2, pb2, 1, Kk, 8, t);
        stage(sW, MW1, mw1, CKc, 23, MP1, t);
        stage(sW, MB1, mb1, 1, CKc, 16, t);
        stage(sW, MW2, mw2, CKc, CKc, MP2, t);
        stage(sW, MB2, mb2, 1, CKc, 16, t);
        stage(sW, SW1, sw1, Kk, 23, SP1, t);
        stage(sW, SB1, sb1, 1, Kk, 8, t);
        stage(sW, SW2, sw2, Kk, Kk, SP2, t);
        stage(sW, SB2, sb2, 1, Kk, 8, t);
        stage(sW, GW1, gw1, Kk, Kk, GP1, t);
        stage(sW, GB1, gb1, 1, Kk, 8, t);
        stage(sW, GW2, gw2, 1, Kk, 8, t);
        stage(sW, GB2, gb2, 1, 1, 4, t);
    }
    __syncthreads();

    const int tid = blockIdx.x * blockDim.x + threadIdx.x;
    const int b  = tid / HWc;
    const int hw = tid - b * HWc;

    const float C0 = 0.06349363593424097f;   // (2*pi)^{-3/2}

    // Per-pixel carried state.
    float pi[Kk], mu[CKc], rinv[Kk];         // rinv = 1/sigma
#pragma unroll
    for (int k = 0; k < Kk; k++) { pi[k] = 0.2f; rinv[k] = 1.0f; }
    {
        const float* mp = mu0 + (size_t)b * CKc * HWc + hw;
#pragma unroll
        for (int j = 0; j < CKc; j++) mu[j] = mp[(size_t)j * HWc];
    }

    const float* fbase = frames + ((size_t)b * Ss * Cc) * HWc + hw;
    float x[Cc];
#pragma unroll
    for (int c = 0; c < Cc; c++) x[c] = fbase[(size_t)c * HWc];

#pragma unroll 1
    for (int s = 0; s < Ss; s++) {
        // Opaque per-iteration LDS offset: runtime value is always 0, but the
        // compiler cannot prove it, so weight loads below are loop-VARIANT and
        // machine-LICM cannot hoist them into whole-loop-live registers
        // (round 2: hoisting -> 188 VGPR -> 2 waves/SIMD).
        unsigned woff = 0;
        asm volatile("" : "+v"(woff));
        woff &= ~3u;   // provably 16B-aligned -> ds_read_b128 merges still legal
#define LW(IDX) sW[woff + (IDX)]

        // Prefetch next frame's pixel (hides global latency behind this step).
        float xn[Cc];
        if (s + 1 < Ss) {
            const float* fp = fbase + ((size_t)(s + 1) * Cc) * HWc;
#pragma unroll
            for (int c = 0; c < Cc; c++) xn[c] = fp[(size_t)c * HWc];
        }

        // ---- density(x; mu, 1/rinv) ----
        float dens[Kk];
#pragma unroll
        for (int k = 0; k < Kk; k++) {
            float inv_s2 = rinv[k] * rinv[k];
            float d0 = x[0] - mu[k * Cc + 0];
            float d1 = x[1] - mu[k * Cc + 1];
            float d2 = x[2] - mu[k * Cc + 2];
            float dist = d0 * d0 + d1 * d1 + d2 * d2;
            float coef = C0 * inv_s2 * rinv[k];            // C0 * rinv^3
            dens[k] = coef * __expf(-0.5f * dist * inv_s2);
        }

        float alpha[Kk], rho[Kk];
#pragma unroll
        for (int k = 0; k < Kk; k++) { alpha[k] = pi[k] * dens[k]; rho[k] = alpha[k] * dens[k]; }

        // ---- pi MLP (10 -> 5 -> 5) + softmax over K ----
        float piN[Kk];
        {
            float in[2 * Kk];
#pragma unroll
            for (int k = 0; k < Kk; k++) { in[k] = pi[k]; in[Kk + k] = alpha[k]; }
            float h[Kk];
#pragma unroll
            for (int j = 0; j < Kk; j++) {
                float a = LW(PB1 + j);
#pragma unroll
                for (int i = 0; i < 2 * Kk; i++) a = fmaf(LW(PW1 + j * PP1 + i), in[i], a);
                h[j] = relu(a);
            }
            float o[Kk];
            float m = -1e30f;
#pragma unroll
            for (int j = 0; j < Kk; j++) {
                float a = LW(PB2 + j);
#pragma unroll
                for (int i = 0; i < Kk; i++) a = fmaf(LW(PW2 + j * PP2 + i), h[i], a);
                o[j] = a; m = fmaxf(m, a);
            }
            float sum = 0.0f;
#pragma unroll
            for (int j = 0; j < Kk; j++) { o[j] = __expf(o[j] - m); sum += o[j]; }
            float r = rcpf(sum);
#pragma unroll
            for (int j = 0; j < Kk; j++) piN[j] = o[j] * r;
        }

        // ---- shared input vector for mu/sigma MLPs ----
        float in23[23];
        in23[0] = x[0]; in23[1] = x[1]; in23[2] = x[2];
#pragma unroll
        for (int j = 0; j < CKc; j++) in23[3 + j] = mu[j];
#pragma unroll
        for (int k = 0; k < Kk; k++) in23[18 + k] = rho[k];

        // ---- mu MLP (23 -> 15 -> 15), sigmoid ----
        float muN[CKc];
        {
            float h[CKc];
#pragma unroll
            for (int j = 0; j < CKc; j++) {
                float a = LW(MB1 + j);
#pragma unroll
                for (int i = 0; i < 23; i++) a = fmaf(LW(MW1 + j * MP1 + i), in23[i], a);
                h[j] = relu(a);
            }
#pragma unroll
            for (int j = 0; j < CKc; j++) {
                float a = LW(MB2 + j);
#pragma unroll
                for (int i = 0; i < CKc; i++) a = fmaf(LW(MW2 + j * MP2 + i), h[i], a);
                muN[j] = sigm(a);
            }
        }

        // ---- sigma MLP (23 -> 5 -> 5): rinvN = exp(-relu(a)) ----
#pragma unroll
        for (int j = 0; j < CKc; j++) in23[3 + j] = muN[j];   // reuse x, rho slots
        float rinvN[Kk];
        {
            float h[Kk];
#pragma unroll
            for (int j = 0; j < Kk; j++) {
                float a = LW(SB1 + j);
#pragma unroll
                for (int i = 0; i < 23; i++) a = fmaf(LW(SW1 + j * SP1 + i), in23[i], a);
                h[j] = relu(a);
            }
#pragma unroll
            for (int j = 0; j < Kk; j++) {
                float a = LW(SB2 + j);
#pragma unroll
                for (int i = 0; i < Kk; i++) a = fmaf(LW(SW2 + j * SP2 + i), h[i], a);
                rinvN[j] = __expf(-relu(a));
            }
        }

        // ---- dens2(x; muN, 1/rinvN), gamma MLP (5 -> 5 -> 1), sigmoid ----
        float gin[Kk];
#pragma unroll
        for (int k = 0; k < Kk; k++) {
            float inv_s2 = rinvN[k] * rinvN[k];
            float d0 = x[0] - muN[k * Cc + 0];
            float d1 = x[1] - muN[k * Cc + 1];
            float d2 = x[2] - muN[k * Cc + 2];
            float dist = d0 * d0 + d1 * d1 + d2 * d2;
            float coef = C0 * inv_s2 * rinvN[k];
            gin[k] = piN[k] * (coef * __expf(-0.5f * dist * inv_s2));
        }
        {
            float h[Kk];
#pragma unroll
            for (int j = 0; j < Kk; j++) {
                float a = LW(GB1 + j);
#pragma unroll
                for (int i = 0; i < Kk; i++) a = fmaf(LW(GW1 + j * GP1 + i), gin[i], a);
                h[j] = relu(a);
            }
            float go = LW(GB2);
#pragma unroll
            for (int i = 0; i < Kk; i++) go = fmaf(LW(GW2 + i), h[i], go);
            out[(size_t)(b * Ss + s) * HWc + hw] = sigm(go);
        }
#undef LW

        // ---- carry state ----
#pragma unroll
        for (int k = 0; k < Kk; k++) { pi[k] = piN[k]; rinv[k] = rinvN[k]; }
#pragma unroll
        for (int j = 0; j < CKc; j++) mu[j] = muN[j];
#pragma unroll
        for (int c = 0; c < Cc; c++) x[c] = xn[c];
    }
}

} // namespace

extern "C" void kernel_launch(void* const* d_in, const int* in_sizes, int n_in,
                              void* d_out, int out_size, void* d_ws, size_t ws_size,
                              hipStream_t stream) {
    const float* frames = (const float*)d_in[0];
    const float* mu0    = (const float*)d_in[2];
    const float* pw1 = (const float*)d_in[3];
    const float* pb1 = (const float*)d_in[4];
    const float* pw2 = (const float*)d_in[5];
    const float* pb2 = (const float*)d_in[6];
    const float* mw1 = (const float*)d_in[7];
    const float* mb1 = (const float*)d_in[8];
    const float* mw2 = (const float*)d_in[9];
    const float* mb2 = (const float*)d_in[10];
    const float* sw1 = (const float*)d_in[11];
    const float* sb1 = (const float*)d_in[12];
    const float* sw2 = (const float*)d_in[13];
    const float* sb2 = (const float*)d_in[14];
    const float* gw1 = (const float*)d_in[15];
    const float* gb1 = (const float*)d_in[16];
    const float* gw2 = (const float*)d_in[17];
    const float* gb2 = (const float*)d_in[18];
    float* out = (float*)d_out;

    const int total = Bb * HWc;          // 589,824 pixels
    const int block = 256;
    const int grid = (total + block - 1) / block;   // 2304 blocks

    gmm_seq_kernel<<<grid, block, 0, stream>>>(
        frames, mu0,
        pw1, pb1, pw2, pb2,
        mw1, mb1, mw2, mb2,
        sw1, sb1, sw2, sb2,
        gw1, gb1, gw2, gb2,
        out);
}

// Round 5
// 315.862 us; speedup vs baseline: 3.5466x; 1.0652x over previous
//
#include <hip/hip_runtime.h>

// GMMNet: B=4,S=8,C=3,H=W=384,K=5. Pointwise per pixel; scan over S carries
// per-pixel state (pi[5], mu[15], rinv[5]=1/sigma) in registers.
//
// Round 5: 2 pixels/thread packed into float2 -> v_pk_fma_f32 (full-rate
// packed fp32 on gfx950) halves FMA issue count per pixel AND gives each
// thread two independent dependency chains (round 4 showed ~half of
// VALUBusy was issue interlock). Weights are scalar broadcasts (op_sel
// splat); global loads/stores become 8B/lane float2. Opaque-woff anti-LICM
// trick retained (round 2: hoisting -> 188 VGPR; round 3: capping -> spill).

namespace {

constexpr int Kk = 5;
constexpr int Cc = 3;
constexpr int CKc = 15;   // C*K
constexpr int Bb = 4;
constexpr int Ss = 8;
constexpr int HWc = 384 * 384;
constexpr int HW2 = HWc / 2;          // pixel-pairs per image

typedef float v2f __attribute__((ext_vector_type(2)));

// LDS layout (float offsets); bases/pitches %4==0.
constexpr int PW1 = 0,   PP1 = 12;  // pi_w1  5x10
constexpr int PB1 = 60;             // pi_b1  5 (pad 8)
constexpr int PW2 = 68,  PP2 = 8;   // pi_w2  5x5
constexpr int PB2 = 108;            // pi_b2  5 (pad 8)
constexpr int MW1 = 116, MP1 = 24;  // mu_w1  15x23
constexpr int MB1 = 476;            // mu_b1  15 (pad 16)
constexpr int MW2 = 492, MP2 = 16;  // mu_w2  15x15
constexpr int MB2 = 732;            // mu_b2  15 (pad 16)
constexpr int SW1 = 748, SP1 = 24;  // sg_w1  5x23
constexpr int SB1 = 868;            // sg_b1  5 (pad 8)
constexpr int SW2 = 876, SP2 = 8;   // sg_w2  5x5
constexpr int SB2 = 916;            // sg_b2  5 (pad 8)
constexpr int GW1 = 924, GP1 = 8;   // ga_w1  5x5
constexpr int GB1 = 964;            // ga_b1  5 (pad 8)
constexpr int GW2 = 972;            // ga_w2  5 (pad 8)
constexpr int GB2 = 980;            // ga_b2  1 (pad 4)
constexpr int WTOT = 984;           // 3936 B

__device__ __forceinline__ float rcpf(float x) { return __builtin_amdgcn_rcpf(x); }

__device__ __forceinline__ v2f vsplat(float w) { v2f r = {w, w}; return r; }
__device__ __forceinline__ v2f vfma(v2f a, v2f b, v2f c) { return __builtin_elementwise_fma(a, b, c); }
// weight (scalar, broadcast) * packed-pixel + acc  -> v_pk_fma_f32 w/ op_sel splat
__device__ __forceinline__ v2f wfma(float w, v2f x, v2f c) { return vfma(vsplat(w), x, c); }
__device__ __forceinline__ v2f vexp(v2f v) { v2f r; r.x = __expf(v.x); r.y = __expf(v.y); return r; }
__device__ __forceinline__ v2f vrcp(v2f v) { v2f r; r.x = rcpf(v.x); r.y = rcpf(v.y); return r; }
__device__ __forceinline__ v2f vmax(v2f a, v2f b) { return __builtin_elementwise_max(a, b); }
__device__ __forceinline__ v2f vrelu(v2f a) { return vmax(a, vsplat(0.0f)); }
__device__ __forceinline__ v2f vsigm(v2f a) { return vrcp(vsplat(1.0f) + vexp(-a)); }

__device__ __forceinline__ void stage(float* W, int dst, const float* __restrict__ src,
                                      int rows, int cols, int pitch, int tid) {
    for (int t = tid; t < rows * pitch; t += 256) {
        int r = t / pitch, c = t - r * pitch;
        W[dst + t] = (c < cols) ? src[r * cols + c] : 0.0f;
    }
}

__global__ __launch_bounds__(256) void gmm_seq_kernel(
    const float* __restrict__ frames,
    const float* __restrict__ mu0,
    const float* __restrict__ pw1, const float* __restrict__ pb1,
    const float* __restrict__ pw2, const float* __restrict__ pb2,
    const float* __restrict__ mw1, const float* __restrict__ mb1,
    const float* __restrict__ mw2, const float* __restrict__ mb2,
    const float* __restrict__ sw1, const float* __restrict__ sb1,
    const float* __restrict__ sw2, const float* __restrict__ sb2,
    const float* __restrict__ gw1, const float* __restrict__ gb1,
    const float* __restrict__ gw2, const float* __restrict__ gb2,
    float* __restrict__ out)
{
    __shared__ float sW[WTOT];
    {
        const int t = threadIdx.x;
        stage(sW, PW1, pw1, Kk, 2 * Kk, PP1, t);
        stage(sW, PB1, pb1, 1, Kk, 8, t);
        stage(sW, PW2, pw2, Kk, Kk, PP2, t);
        stage(sW, PB2, pb2, 1, Kk, 8, t);
        stage(sW, MW1, mw1, CKc, 23, MP1, t);
        stage(sW, MB1, mb1, 1, CKc, 16, t);
        stage(sW, MW2, mw2, CKc, CKc, MP2, t);
        stage(sW, MB2, mb2, 1, CKc, 16, t);
        stage(sW, SW1, sw1, Kk, 23, SP1, t);
        stage(sW, SB1, sb1, 1, Kk, 8, t);
        stage(sW, SW2, sw2, Kk, Kk, SP2, t);
        stage(sW, SB2, sb2, 1, Kk, 8, t);
        stage(sW, GW1, gw1, Kk, Kk, GP1, t);
        stage(sW, GB1, gb1, 1, Kk, 8, t);
        stage(sW, GW2, gw2, 1, Kk, 8, t);
        stage(sW, GB2, gb2, 1, 1, 4, t);
    }
    __syncthreads();

    const int t2 = blockIdx.x * blockDim.x + threadIdx.x;   // one thread = 2 adjacent px
    const int b   = t2 / HW2;
    const int rem = t2 - b * HW2;

    const float C0 = 0.06349363593424097f;   // (2*pi)^{-3/2}

    // Per-pixel-pair carried state.
    v2f pi[Kk], mu[CKc], rinv[Kk];           // rinv = 1/sigma
#pragma unroll
    for (int k = 0; k < Kk; k++) { pi[k] = vsplat(0.2f); rinv[k] = vsplat(1.0f); }
    {
        const float* mp = mu0 + (size_t)b * CKc * HWc;
#pragma unroll
        for (int j = 0; j < CKc; j++)
            mu[j] = reinterpret_cast<const v2f*>(mp + (size_t)j * HWc)[rem];
    }

    const float* fbase = frames + ((size_t)b * Ss * Cc) * HWc;
    v2f x[Cc];
#pragma unroll
    for (int c = 0; c < Cc; c++)
        x[c] = reinterpret_cast<const v2f*>(fbase + (size_t)c * HWc)[rem];

#pragma unroll 1
    for (int s = 0; s < Ss; s++) {
        // Opaque per-iteration LDS offset: prevents machine-LICM from hoisting
        // the ~871 weight reads into whole-loop-live registers.
        unsigned woff = 0;
        asm volatile("" : "+v"(woff));
        woff &= ~3u;
#define LW(IDX) sW[woff + (IDX)]

        // Prefetch next frame's pixels.
        v2f xn[Cc];
        if (s + 1 < Ss) {
            const float* fp = fbase + ((size_t)(s + 1) * Cc) * HWc;
#pragma unroll
            for (int c = 0; c < Cc; c++)
                xn[c] = reinterpret_cast<const v2f*>(fp + (size_t)c * HWc)[rem];
        }

        // ---- density(x; mu, 1/rinv) ----
        v2f dens[Kk];
#pragma unroll
        for (int k = 0; k < Kk; k++) {
            v2f inv_s2 = rinv[k] * rinv[k];
            v2f d0 = x[0] - mu[k * Cc + 0];
            v2f d1 = x[1] - mu[k * Cc + 1];
            v2f d2 = x[2] - mu[k * Cc + 2];
            v2f dist = vfma(d0, d0, vfma(d1, d1, d2 * d2));
            v2f coef = vsplat(C0) * inv_s2 * rinv[k];      // C0 * rinv^3
            dens[k] = coef * vexp(vsplat(-0.5f) * dist * inv_s2);
        }

        v2f alpha[Kk], rho[Kk];
#pragma unroll
        for (int k = 0; k < Kk; k++) { alpha[k] = pi[k] * dens[k]; rho[k] = alpha[k] * dens[k]; }

        // ---- pi MLP (10 -> 5 -> 5) + softmax over K ----
        v2f piN[Kk];
        {
            v2f h[Kk];
#pragma unroll
            for (int j = 0; j < Kk; j++) {
                v2f a = vsplat(LW(PB1 + j));
#pragma unroll
                for (int i = 0; i < Kk; i++) a = wfma(LW(PW1 + j * PP1 + i), pi[i], a);
#pragma unroll
                for (int i = 0; i < Kk; i++) a = wfma(LW(PW1 + j * PP1 + Kk + i), alpha[i], a);
                h[j] = vrelu(a);
            }
            v2f o[Kk];
            v2f m = vsplat(-1e30f);
#pragma unroll
            for (int j = 0; j < Kk; j++) {
                v2f a = vsplat(LW(PB2 + j));
#pragma unroll
                for (int i = 0; i < Kk; i++) a = wfma(LW(PW2 + j * PP2 + i), h[i], a);
                o[j] = a; m = vmax(m, a);
            }
            v2f sum = vsplat(0.0f);
#pragma unroll
            for (int j = 0; j < Kk; j++) { o[j] = vexp(o[j] - m); sum = sum + o[j]; }
            v2f r = vrcp(sum);
#pragma unroll
            for (int j = 0; j < Kk; j++) piN[j] = o[j] * r;
        }

        // ---- mu MLP (23 -> 15 -> 15), sigmoid ----
        // Layer-1 inputs read directly from x / mu / rho (no packed in23 array
        // -> saves ~46 VGPRs of copies).
        v2f muN[CKc];
        {
            v2f h[CKc];
#pragma unroll
            for (int j = 0; j < CKc; j++) {
                v2f a = vsplat(LW(MB1 + j));
#pragma unroll
                for (int i = 0; i < Cc; i++)  a = wfma(LW(MW1 + j * MP1 + i), x[i], a);
#pragma unroll
                for (int i = 0; i < CKc; i++) a = wfma(LW(MW1 + j * MP1 + 3 + i), mu[i], a);
#pragma unroll
                for (int i = 0; i < Kk; i++)  a = wfma(LW(MW1 + j * MP1 + 18 + i), rho[i], a);
                h[j] = vrelu(a);
            }
#pragma unroll
            for (int j = 0; j < CKc; j++) {
                v2f a = vsplat(LW(MB2 + j));
#pragma unroll
                for (int i = 0; i < CKc; i++) a = wfma(LW(MW2 + j * MP2 + i), h[i], a);
                muN[j] = vsigm(a);
            }
        }

        // ---- sigma MLP (23 -> 5 -> 5): rinvN = exp(-relu(a)) = 1/sigma_new ----
        v2f rinvN[Kk];
        {
            v2f h[Kk];
#pragma unroll
            for (int j = 0; j < Kk; j++) {
                v2f a = vsplat(LW(SB1 + j));
#pragma unroll
                for (int i = 0; i < Cc; i++)  a = wfma(LW(SW1 + j * SP1 + i), x[i], a);
#pragma unroll
                for (int i = 0; i < CKc; i++) a = wfma(LW(SW1 + j * SP1 + 3 + i), muN[i], a);
#pragma unroll
                for (int i = 0; i < Kk; i++)  a = wfma(LW(SW1 + j * SP1 + 18 + i), rho[i], a);
                h[j] = vrelu(a);
            }
#pragma unroll
            for (int j = 0; j < Kk; j++) {
                v2f a = vsplat(LW(SB2 + j));
#pragma unroll
                for (int i = 0; i < Kk; i++) a = wfma(LW(SW2 + j * SP2 + i), h[i], a);
                rinvN[j] = vexp(-vrelu(a));
            }
        }

        // ---- dens2(x; muN, 1/rinvN), gamma MLP (5 -> 5 -> 1), sigmoid ----
        v2f gin[Kk];
#pragma unroll
        for (int k = 0; k < Kk; k++) {
            v2f inv_s2 = rinvN[k] * rinvN[k];
            v2f d0 = x[0] - muN[k * Cc + 0];
            v2f d1 = x[1] - muN[k * Cc + 1];
            v2f d2 = x[2] - muN[k * Cc + 2];
            v2f dist = vfma(d0, d0, vfma(d1, d1, d2 * d2));
            v2f coef = vsplat(C0) * inv_s2 * rinvN[k];
            gin[k] = piN[k] * (coef * vexp(vsplat(-0.5f) * dist * inv_s2));
        }
        {
            v2f h[Kk];
#pragma unroll
            for (int j = 0; j < Kk; j++) {
                v2f a = vsplat(LW(GB1 + j));
#pragma unroll
                for (int i = 0; i < Kk; i++) a = wfma(LW(GW1 + j * GP1 + i), gin[i], a);
                h[j] = vrelu(a);
            }
            v2f go = vsplat(LW(GB2));
#pragma unroll
            for (int i = 0; i < Kk; i++) go = wfma(LW(GW2 + i), h[i], go);
            reinterpret_cast<v2f*>(out + (size_t)(b * Ss + s) * HWc)[rem] = vsigm(go);
        }
#undef LW

        // ---- carry state ----
#pragma unroll
        for (int k = 0; k < Kk; k++) { pi[k] = piN[k]; rinv[k] = rinvN[k]; }
#pragma unroll
        for (int j = 0; j < CKc; j++) mu[j] = muN[j];
#pragma unroll
        for (int c = 0; c < Cc; c++) x[c] = xn[c];
    }
}

} // namespace

extern "C" void kernel_launch(void* const* d_in, const int* in_sizes, int n_in,
                              void* d_out, int out_size, void* d_ws, size_t ws_size,
                              hipStream_t stream) {
    const float* frames = (const float*)d_in[0];
    const float* mu0    = (const float*)d_in[2];
    const float* pw1 = (const float*)d_in[3];
    const float* pb1 = (const float*)d_in[4];
    const float* pw2 = (const float*)d_in[5];
    const float* pb2 = (const float*)d_in[6];
    const float* mw1 = (const float*)d_in[7];
    const float* mb1 = (const float*)d_in[8];
    const float* mw2 = (const float*)d_in[9];
    const float* mb2 = (const float*)d_in[10];
    const float* sw1 = (const float*)d_in[11];
    const float* sb1 = (const float*)d_in[12];
    const float* sw2 = (const float*)d_in[13];
    const float* sb2 = (const float*)d_in[14];
    const float* gw1 = (const float*)d_in[15];
    const float* gb1 = (const float*)d_in[16];
    const float* gw2 = (const float*)d_in[17];
    const float* gb2 = (const float*)d_in[18];
    float* out = (float*)d_out;

    const int total2 = Bb * HW2;         // 294,912 pixel-pairs
    const int block = 256;
    const int grid = (total2 + block - 1) / block;   // 1152 blocks

    gmm_seq_kernel<<<grid, block, 0, stream>>>(
        frames, mu0,
        pw1, pb1, pw2, pb2,
        mw1, mb1, mw2, mb2,
        sw1, sb1, sw2, sb2,
        gw1, gb1, gw2, gb2,
        out);
}